// Round 2
// baseline (666.154 us; speedup 1.0000x reference)
//
#include <hip/hip_runtime.h>
#include <cstdint>

// Binary ResBlock on MI355X.
// Bit convention: bit = 1 <=> value < 0 (binarize -> -1).
// dot(tap) = 32*valid_words - 2*popc(a^w); main kernels assume all taps valid
// (clamped reads, exact for interior pixels); border fixup kernels overwrite.

#define HWD 128

// ---------------- pack x -> xb : [pixel][8 words], pixel=(n<<14)+(h<<7)+w ---
__global__ __launch_bounds__(256) void pack_x(const float* __restrict__ x,
                                              uint32_t* __restrict__ xb) {
  int id = blockIdx.x * 256 + threadIdx.x;   // 262144
  int w4 = id & 31;
  int wd = (id >> 5) & 7;
  int h  = (id >> 8) & 127;
  int n  = id >> 15;
  const float4* src = (const float4*)(x + ((n * 256 + wd * 32) << 14) + (h << 7) + (w4 << 2));
  uint32_t b0 = 0, b1 = 0, b2 = 0, b3 = 0;
#pragma unroll
  for (int c = 0; c < 32; ++c) {
    float4 v = src[c << 12];   // stride 16384 floats
    b0 |= (v.x < 0.0f ? 1u : 0u) << c;
    b1 |= (v.y < 0.0f ? 1u : 0u) << c;
    b2 |= (v.z < 0.0f ? 1u : 0u) << c;
    b3 |= (v.w < 0.0f ? 1u : 0u) << c;
  }
  int p0 = (n << 14) + (h << 7) + (w4 << 2);
  xb[((p0 + 0) << 3) + wd] = b0;
  xb[((p0 + 1) << 3) + wd] = b1;
  xb[((p0 + 2) << 3) + wd] = b2;
  xb[((p0 + 3) << 3) + wd] = b3;
}

// ---------------- pack weights + concat layer-1 bias -----------------------
// wl1: [4 br][64 oc][5 taps][8 words] = 10240 words
// wl2: [256 oc][9 taps][8 words]      = 18432 words
__global__ __launch_bounds__(256) void pack_w(
    const float* __restrict__ w1, const float* __restrict__ w2,
    const float* __restrict__ w3, const float* __restrict__ w4,
    const float* __restrict__ wc,
    const float* __restrict__ b1, const float* __restrict__ b2,
    const float* __restrict__ b3, const float* __restrict__ b4,
    uint32_t* __restrict__ wl1, uint32_t* __restrict__ wl2,
    float* __restrict__ bcat) {
  int id = blockIdx.x * 256 + threadIdx.x;
  if (id < 10240) {
    int wd  = id & 7;
    int tap = (id >> 3) % 5;
    int oc  = (id / 40) & 63;
    int br  = id / 2560;
    const float* w = (br == 0) ? w1 : (br == 1) ? w2 : (br == 2) ? w3 : w4;
    uint32_t bits = 0;
#pragma unroll
    for (int i = 0; i < 32; ++i) {
      float v = w[(oc * 256 + wd * 32 + i) * 5 + tap];
      bits |= (v < 0.0f ? 1u : 0u) << i;
    }
    wl1[id] = bits;
  } else if (id < 28672) {
    int id2 = id - 10240;
    int wd  = id2 & 7;
    int tap = (id2 >> 3) % 9;
    int oc  = id2 / 72;
    uint32_t bits = 0;
#pragma unroll
    for (int i = 0; i < 32; ++i) {
      float v = wc[(oc * 256 + wd * 32 + i) * 9 + tap];
      bits |= (v < 0.0f ? 1u : 0u) << i;
    }
    wl2[id2] = bits;
  } else if (id < 28928) {
    int c = id - 28672;
    float v = (c < 64) ? b1[c] : (c < 128) ? b2[c - 64]
              : (c < 192) ? b3[c - 128] : b4[c - 192];
    bcat[c] = v;
  }
}

// ---------------- layer 1 main: one branch per block, clamped (no masks) ---
__global__ __launch_bounds__(256) void layer1_main(
    const uint32_t* __restrict__ xb, uint32_t* __restrict__ yb,
    const uint32_t* __restrict__ wl1, const float* __restrict__ bcat,
    const float* __restrict__ a1p) {
  __shared__ uint32_t lw[2560];
  __shared__ float lb[64];
  const int br = blockIdx.x >> 9;
  const int pb = blockIdx.x & 511;
  const int t  = threadIdx.x;
  {
    const uint4* wsrc = (const uint4*)(wl1 + br * 2560);
    uint4* ldst = (uint4*)lw;
    for (int k = t; k < 640; k += 256) ldst[k] = wsrc[k];
    if (t < 64) lb[t] = bcat[br * 64 + t];
  }
  __syncthreads();
  const float a1 = a1p[0];
  int p = pb * 256 + t;
  int w = p & 127, h = (p >> 7) & 127, n = p >> 14;
  const int dil = (br & 1) ? 2 : 1;
  const bool horiz = (br < 2);

  uint4 ia[5], ib[5];
#pragma unroll
  for (int tap = 0; tap < 5; ++tap) {
    int d = dil * (tap - 2);
    int hh = horiz ? h : min(max(h + d, 0), HWD - 1);
    int ww = horiz ? min(max(w + d, 0), HWD - 1) : w;
    const uint4* src = (const uint4*)(xb + (((((n << 7) + hh) << 7) + ww) << 3));
    ia[tap] = src[0];
    ib[tap] = src[1];
  }

  uint32_t bw[2];
#pragma unroll
  for (int half = 0; half < 2; ++half) {
    uint32_t b = 0;
    for (int oc = 0; oc < 32; ++oc) {
      const uint4* wp = (const uint4*)(lw + (half * 32 + oc) * 40);
      int acc = 0;
#pragma unroll
      for (int tap = 0; tap < 5; ++tap) {
        uint4 wa = wp[tap * 2], wb = wp[tap * 2 + 1];
        acc = __popc(ia[tap].x ^ wa.x) + acc;
        acc = __popc(ia[tap].y ^ wa.y) + acc;
        acc = __popc(ia[tap].z ^ wa.z) + acc;
        acc = __popc(ia[tap].w ^ wa.w) + acc;
        acc = __popc(ib[tap].x ^ wb.x) + acc;
        acc = __popc(ib[tap].y ^ wb.y) + acc;
        acc = __popc(ib[tap].z ^ wb.z) + acc;
        acc = __popc(ib[tap].w ^ wb.w) + acc;
      }
      float v = (float)(1280 - 2 * acc) + lb[half * 32 + oc];
      v = v >= 0.0f ? v : a1 * v;
      b |= (v < 0.0f ? 1u : 0u) << oc;
    }
    bw[half] = b;
  }
  *(uint2*)(yb + (p << 3) + br * 2) = make_uint2(bw[0], bw[1]);
}

// ---------------- layer 1 border fixup (masked, overwrites) ----------------
__global__ __launch_bounds__(256) void layer1_fix(
    const uint32_t* __restrict__ xb, uint32_t* __restrict__ yb,
    const uint32_t* __restrict__ wl1, const float* __restrict__ bcat,
    const float* __restrict__ a1p) {
  int id = blockIdx.x * 256 + threadIdx.x;   // 32768
  int br  = id >> 13;
  int rem = id & 8191;
  int e  = rem & 7;
  int e2 = (e < 4) ? e : 120 + e;            // {0,1,2,3,124,125,126,127}
  int o  = (rem >> 3) & 127;
  int n  = rem >> 10;
  int w, h;
  if (br < 2) { w = e2; h = o; } else { h = e2; w = o; }
  const int dil = (br & 1) ? 2 : 1;
  const bool horiz = (br < 2);
  const float a1 = a1p[0];

  uint4 ia[5], ib[5];
  int msk[5]; int nval = 0;
#pragma unroll
  for (int tap = 0; tap < 5; ++tap) {
    int d = dil * (tap - 2);
    int hh = horiz ? h : h + d;
    int ww = horiz ? w + d : w;
    bool v = (hh >= 0) && (hh < HWD) && (ww >= 0) && (ww < HWD);
    msk[tap] = v ? -1 : 0; nval += v ? 1 : 0;
    int hc = min(max(hh, 0), HWD - 1), wc2 = min(max(ww, 0), HWD - 1);
    const uint4* src = (const uint4*)(xb + (((((n << 7) + hc) << 7) + wc2) << 3));
    ia[tap] = src[0]; ib[tap] = src[1];
  }
  int basev = 256 * nval;
  uint32_t bw[2];
#pragma unroll
  for (int half = 0; half < 2; ++half) {
    uint32_t b = 0;
    for (int oc = 0; oc < 32; ++oc) {
      const uint4* wp = (const uint4*)(wl1 + (br * 64 + half * 32 + oc) * 40);
      int acc = 0;
#pragma unroll
      for (int tap = 0; tap < 5; ++tap) {
        uint4 wa = wp[tap * 2], wb = wp[tap * 2 + 1];
        int ta = __popc(ia[tap].x ^ wa.x) + __popc(ia[tap].y ^ wa.y) +
                 __popc(ia[tap].z ^ wa.z) + __popc(ia[tap].w ^ wa.w) +
                 __popc(ib[tap].x ^ wb.x) + __popc(ib[tap].y ^ wb.y) +
                 __popc(ib[tap].z ^ wb.z) + __popc(ib[tap].w ^ wb.w);
        acc += ta & msk[tap];
      }
      float v = (float)(basev - 2 * acc) + bcat[br * 64 + half * 32 + oc];
      v = v >= 0.0f ? v : a1 * v;
      b |= (v < 0.0f ? 1u : 0u) << oc;
    }
    bw[half] = b;
  }
  int p = (n << 14) + (h << 7) + w;
  *(uint2*)(yb + (p << 3) + br * 2) = make_uint2(bw[0], bw[1]);
}

// ---------------- layer 2 main: 64-oc chunk per block, clamped -------------
__global__ __launch_bounds__(256) void layer2_main(
    const uint32_t* __restrict__ yb, const uint32_t* __restrict__ wl2,
    const float* __restrict__ bc, const float* __restrict__ a2p,
    const float* __restrict__ x, float* __restrict__ out) {
  __shared__ uint32_t lw[4608];   // 64 oc * 72 words = 18 KB
  __shared__ float lb[64];
  const int ch = blockIdx.x >> 9;   // 0..3
  const int pb = blockIdx.x & 511;
  const int t  = threadIdx.x;
  {
    const uint4* wsrc = (const uint4*)(wl2 + ch * 4608);
    uint4* ldst = (uint4*)lw;
    for (int k = t; k < 1152; k += 256) ldst[k] = wsrc[k];
    if (t < 64) lb[t] = bc[ch * 64 + t];
  }
  __syncthreads();
  const float a2 = a2p[0];
  int p = pb * 256 + t;
  int w = p & 127, h = (p >> 7) & 127, n = p >> 14;

  uint4 ia[9], ib[9];
#pragma unroll
  for (int ky = 0; ky < 3; ++ky) {
#pragma unroll
    for (int kx = 0; kx < 3; ++kx) {
      int tap = ky * 3 + kx;
      int hh = min(max(h + ky - 1, 0), HWD - 1);
      int ww = min(max(w + kx - 1, 0), HWD - 1);
      const uint4* src = (const uint4*)(yb + (((((n << 7) + hh) << 7) + ww) << 3));
      ia[tap] = src[0]; ib[tap] = src[1];
    }
  }
  const float* xs = x + (n << 22) + (ch << 20) + (h << 7) + w;
  float* os = out + (n << 22) + (ch << 20) + (h << 7) + w;

  for (int oc = 0; oc < 64; ++oc) {
    const uint4* wp = (const uint4*)(lw + oc * 72);
    int acc = 0;
#pragma unroll
    for (int tap = 0; tap < 9; ++tap) {
      uint4 wa = wp[tap * 2], wb = wp[tap * 2 + 1];
      acc = __popc(ia[tap].x ^ wa.x) + acc;
      acc = __popc(ia[tap].y ^ wa.y) + acc;
      acc = __popc(ia[tap].z ^ wa.z) + acc;
      acc = __popc(ia[tap].w ^ wa.w) + acc;
      acc = __popc(ib[tap].x ^ wb.x) + acc;
      acc = __popc(ib[tap].y ^ wb.y) + acc;
      acc = __popc(ib[tap].z ^ wb.z) + acc;
      acc = __popc(ib[tap].w ^ wb.w) + acc;
    }
    float v = (float)(2304 - 2 * acc) + lb[oc];
    v = v >= 0.0f ? v : a2 * v;
    os[oc << 14] = v + xs[oc << 14];
  }
}

// ---------------- layer 2 border fixup (masked, overwrites) ----------------
__global__ __launch_bounds__(256) void layer2_fix(
    const uint32_t* __restrict__ yb, const uint32_t* __restrict__ wl2,
    const float* __restrict__ bc, const float* __restrict__ a2p,
    const float* __restrict__ x, float* __restrict__ out) {
  int id = blockIdx.x * 256 + threadIdx.x;   // 32768
  int chunk = id >> 12;                      // 8 chunks of 32 oc
  int k = id & 4095;
  if (k >= 4064) return;
  int n = k / 508, r = k % 508;
  int h, w;
  if (r < 128)      { h = 0;   w = r; }
  else if (r < 256) { h = 127; w = r - 128; }
  else if (r < 382) { w = 0;   h = r - 255; }
  else              { w = 127; h = r - 381; }
  const float a2 = a2p[0];

  uint4 ia[9], ib[9];
  int msk[9]; int nval = 0;
#pragma unroll
  for (int ky = 0; ky < 3; ++ky) {
#pragma unroll
    for (int kx = 0; kx < 3; ++kx) {
      int tap = ky * 3 + kx;
      int hh = h + ky - 1, ww = w + kx - 1;
      bool v = (hh >= 0) && (hh < HWD) && (ww >= 0) && (ww < HWD);
      msk[tap] = v ? -1 : 0; nval += v ? 1 : 0;
      int hc = min(max(hh, 0), HWD - 1), wc2 = min(max(ww, 0), HWD - 1);
      const uint4* src = (const uint4*)(yb + (((((n << 7) + hc) << 7) + wc2) << 3));
      ia[tap] = src[0]; ib[tap] = src[1];
    }
  }
  int basev = 256 * nval;
  const float* xs = x + (n << 22) + (h << 7) + w;
  float* os = out + (n << 22) + (h << 7) + w;
  for (int oc = 0; oc < 32; ++oc) {
    int ocg = chunk * 32 + oc;
    const uint4* wp = (const uint4*)(wl2 + ocg * 72);
    int acc = 0;
#pragma unroll
    for (int tap = 0; tap < 9; ++tap) {
      uint4 wa = wp[tap * 2], wb = wp[tap * 2 + 1];
      int ta = __popc(ia[tap].x ^ wa.x) + __popc(ia[tap].y ^ wa.y) +
               __popc(ia[tap].z ^ wa.z) + __popc(ia[tap].w ^ wa.w) +
               __popc(ib[tap].x ^ wb.x) + __popc(ib[tap].y ^ wb.y) +
               __popc(ib[tap].z ^ wb.z) + __popc(ib[tap].w ^ wb.w);
      acc += ta & msk[tap];
    }
    float v = (float)(basev - 2 * acc) + bc[ocg];
    v = v >= 0.0f ? v : a2 * v;
    os[ocg << 14] = v + xs[ocg << 14];
  }
}

extern "C" void kernel_launch(void* const* d_in, const int* in_sizes, int n_in,
                              void* d_out, int out_size, void* d_ws, size_t ws_size,
                              hipStream_t stream) {
  const float* x  = (const float*)d_in[0];
  const float* w1 = (const float*)d_in[1];
  const float* b1 = (const float*)d_in[2];
  const float* w2 = (const float*)d_in[3];
  const float* b2 = (const float*)d_in[4];
  const float* w3 = (const float*)d_in[5];
  const float* b3 = (const float*)d_in[6];
  const float* w4 = (const float*)d_in[7];
  const float* b4 = (const float*)d_in[8];
  const float* a1 = (const float*)d_in[9];
  const float* wc = (const float*)d_in[10];
  const float* bc = (const float*)d_in[11];
  const float* a2 = (const float*)d_in[12];
  float* out = (float*)d_out;

  uint32_t* ws  = (uint32_t*)d_ws;
  uint32_t* xb  = ws;                      // 1 M words
  uint32_t* yb  = ws + (1 << 20);          // 1 M words
  uint32_t* wl1 = ws + (2 << 20);          // 10240
  uint32_t* wl2 = wl1 + 10240;             // 18432
  float*    bcat = (float*)(wl2 + 18432);  // 256

  pack_x<<<1024, 256, 0, stream>>>(x, xb);
  pack_w<<<113, 256, 0, stream>>>(w1, w2, w3, w4, wc, b1, b2, b3, b4, wl1, wl2, bcat);
  layer1_main<<<2048, 256, 0, stream>>>(xb, yb, wl1, bcat, a1);
  layer1_fix<<<128, 256, 0, stream>>>(xb, yb, wl1, bcat, a1);
  layer2_main<<<2048, 256, 0, stream>>>(yb, wl2, bc, a2, x, out);
  layer2_fix<<<128, 256, 0, stream>>>(yb, wl2, bc, a2, x, out);
}